// Round 1
// baseline (1062.178 us; speedup 1.0000x reference)
//
#include <hip/hip_runtime.h>
#include <cstddef>

typedef __attribute__((ext_vector_type(8))) short short8;
typedef __attribute__((ext_vector_type(4))) float f32x4;

#define MFMA16(a, b, c) __builtin_amdgcn_mfma_f32_16x16x32_bf16((a), (b), (c), 0, 0, 0)

__device__ __forceinline__ unsigned short f2bf(float f) {
    unsigned u = __float_as_uint(f);
    u = (u + 0x7fffu + ((u >> 16) & 1u)) >> 16;
    return (unsigned short)u;
}
__device__ __forceinline__ float bf2f(unsigned short s) {
    return __uint_as_float(((unsigned)s) << 16);
}
__device__ __forceinline__ float sigm(float v) { return 1.f / (1.f + __expf(-v)); }
__device__ __forceinline__ float tanh_(float v) {
    float a = fabsf(v);
    float e = __expf(-2.f * a);
    float t = (1.f - e) / (1.f + e);
    return v < 0.f ? -t : t;
}

// ============================================================================
// Kernel 1: fused 2-layer GRU over T=60 steps.
// 512 blocks x 256 threads. Block owns 4 samples (rows 4..15 of the MFMA tile
// are duplicates of rows 0..3 -> harmless, finite). Wave w owns hidden units
// j = 16w..16w+15 (all 3 gates). h kept in LDS as bf16 hi/lo, double-buffered,
// XOR-swizzled so A-fragment ds_read_b128 is conflict-free.
// Split-bf16: W*h ~= Whi*hhi + Whi*hlo + Wlo*hhi  (fp32-grade accuracy).
// ============================================================================
__global__ void gru_kernel(const float* __restrict__ x,
                           const float* __restrict__ Wih0, const float* __restrict__ Whh0,
                           const float* __restrict__ bih0, const float* __restrict__ bhh0,
                           const float* __restrict__ Wih1, const float* __restrict__ Whh1,
                           const float* __restrict__ bih1, const float* __restrict__ bhh1,
                           float* __restrict__ xhid) {
    __shared__ __align__(16) float xs[4 * 360];
    __shared__ __align__(16) unsigned short h0h[2][1024], h0l[2][1024];
    __shared__ __align__(16) unsigned short h1h[2][1024], h1l[2][1024];

    const int tid  = threadIdx.x;
    const int w    = tid >> 6;
    const int lane = tid & 63;
    const int c    = lane & 15;   // A row / C col
    const int q    = lane >> 4;   // quarter
    const int jj   = w * 16 + c;  // hidden unit column this lane produces

    {
        const float* xsrc = x + (size_t)blockIdx.x * 4 * 360;
        for (int i = tid; i < 1440; i += 256) xs[i] = xsrc[i];
        for (int i = tid; i < 1024; i += 256) {
            h0h[0][i] = 0; h0l[0][i] = 0; h1h[0][i] = 0; h1l[0][i] = 0;
        }
    }

    // ---- static per-wave B fragments (registers) ----
    short8 B0hh[3][2], B0hl[3][2];   // layer0 Whh  hi/lo  [gate][ktile]
    short8 B1ih[3][2], B1il[3][2];   // layer1 Wih  hi/lo
    short8 B1hh[3][2], B1hl[3][2];   // layer1 Whh  hi/lo
    short8 B0c[3];                   // layer0 Wih K-concat [Whi|Whi|Wlo]

#pragma unroll
    for (int g = 0; g < 3; ++g) {
        const int o = g * 64 + jj;
#pragma unroll
        for (int kt = 0; kt < 2; ++kt) {
            const int k0 = kt * 32 + q * 8;
#pragma unroll
            for (int e = 0; e < 8; ++e) {
                float v; unsigned short hi;
                v = Whh0[o * 64 + k0 + e]; hi = f2bf(v);
                B0hh[g][kt][e] = (short)hi; B0hl[g][kt][e] = (short)f2bf(v - bf2f(hi));
                v = Wih1[o * 64 + k0 + e]; hi = f2bf(v);
                B1ih[g][kt][e] = (short)hi; B1il[g][kt][e] = (short)f2bf(v - bf2f(hi));
                v = Whh1[o * 64 + k0 + e]; hi = f2bf(v);
                B1hh[g][kt][e] = (short)hi; B1hl[g][kt][e] = (short)f2bf(v - bf2f(hi));
            }
        }
#pragma unroll
        for (int e = 0; e < 8; ++e) {
            const int ks = q * 8 + e;
            unsigned short bv = 0;
            if (ks < 6)       bv = f2bf(Wih0[o * 6 + ks]);
            else if (ks < 12) bv = f2bf(Wih0[o * 6 + ks - 6]);
            else if (ks < 18) {
                const float v = Wih0[o * 6 + ks - 12];
                const unsigned short hi = f2bf(v);
                bv = f2bf(v - bf2f(hi));
            }
            B0c[g][e] = (short)bv;
        }
    }

    const float br0 = bih0[jj] + bhh0[jj];
    const float bz0 = bih0[64 + jj] + bhh0[64 + jj];
    const float bi0 = bih0[128 + jj];
    const float bh0 = bhh0[128 + jj];
    const float br1 = bih1[jj] + bhh1[jj];
    const float bz1 = bih1[64 + jj] + bhh1[64 + jj];
    const float bi1 = bih1[128 + jj];
    const float bh1 = bhh1[128 + jj];

    __syncthreads();

    const int ka = q * 8;
    const int swzA0 = c * 64 + (ka ^ ((c & 7) << 3));         // ktile0 frag addr
    const int swzA1 = c * 64 + ((32 + ka) ^ ((c & 7) << 3));  // ktile1 frag addr

    int buf = 0;
    for (int t = 0; t < 60; ++t) {
        // ======================= layer 0 =======================
        short8 ah0 = *(const short8*)&h0h[buf][swzA0];
        short8 ah1 = *(const short8*)&h0h[buf][swzA1];
        short8 al0 = *(const short8*)&h0l[buf][swzA0];
        short8 al1 = *(const short8*)&h0l[buf][swzA1];

        // x K-concat A-fragment [xhi(6)|xlo(6)|xhi(6)|0...]
        const int sx = (c & 3) * 360;
        const float x0 = xs[sx + t],       x1 = xs[sx + 60 + t],  x2 = xs[sx + 120 + t];
        const float x3 = xs[sx + 180 + t], x4 = xs[sx + 240 + t], x5 = xs[sx + 300 + t];
        const unsigned short H0 = f2bf(x0), H1 = f2bf(x1), H2 = f2bf(x2);
        const unsigned short H3 = f2bf(x3), H4 = f2bf(x4), H5 = f2bf(x5);
        const unsigned short L0 = f2bf(x0 - bf2f(H0)), L1 = f2bf(x1 - bf2f(H1));
        const unsigned short L2 = f2bf(x2 - bf2f(H2)), L3 = f2bf(x3 - bf2f(H3));
        const unsigned short L4 = f2bf(x4 - bf2f(H4)), L5 = f2bf(x5 - bf2f(H5));
        short8 ax;
        if (q == 0) {
            ax[0]=(short)H0; ax[1]=(short)H1; ax[2]=(short)H2; ax[3]=(short)H3;
            ax[4]=(short)H4; ax[5]=(short)H5; ax[6]=(short)L0; ax[7]=(short)L1;
        } else if (q == 1) {
            ax[0]=(short)L2; ax[1]=(short)L3; ax[2]=(short)L4; ax[3]=(short)L5;
            ax[4]=(short)H0; ax[5]=(short)H1; ax[6]=(short)H2; ax[7]=(short)H3;
        } else if (q == 2) {
            ax[0]=(short)H4; ax[1]=(short)H5; ax[2]=0; ax[3]=0;
            ax[4]=0; ax[5]=0; ax[6]=0; ax[7]=0;
        } else {
            ax[0]=0; ax[1]=0; ax[2]=0; ax[3]=0; ax[4]=0; ax[5]=0; ax[6]=0; ax[7]=0;
        }

        float hold[4];
#pragma unroll
        for (int i = 0; i < 4; ++i) {
            const int r = q * 4 + i;
            const int ix = r * 64 + (jj ^ ((r & 7) << 3));
            hold[i] = bf2f(h0h[buf][ix]) + bf2f(h0l[buf][ix]);
        }

        f32x4 accr = {br0, br0, br0, br0};
        f32x4 accz = {bz0, bz0, bz0, bz0};
        f32x4 acci = {bi0, bi0, bi0, bi0};
        f32x4 acch = {bh0, bh0, bh0, bh0};

        accr = MFMA16(ah0, B0hh[0][0], accr); accr = MFMA16(ah1, B0hh[0][1], accr);
        accr = MFMA16(al0, B0hh[0][0], accr); accr = MFMA16(al1, B0hh[0][1], accr);
        accr = MFMA16(ah0, B0hl[0][0], accr); accr = MFMA16(ah1, B0hl[0][1], accr);
        accr = MFMA16(ax, B0c[0], accr);

        accz = MFMA16(ah0, B0hh[1][0], accz); accz = MFMA16(ah1, B0hh[1][1], accz);
        accz = MFMA16(al0, B0hh[1][0], accz); accz = MFMA16(al1, B0hh[1][1], accz);
        accz = MFMA16(ah0, B0hl[1][0], accz); accz = MFMA16(ah1, B0hl[1][1], accz);
        accz = MFMA16(ax, B0c[1], accz);

        acci = MFMA16(ax, B0c[2], acci);

        acch = MFMA16(ah0, B0hh[2][0], acch); acch = MFMA16(ah1, B0hh[2][1], acch);
        acch = MFMA16(al0, B0hh[2][0], acch); acch = MFMA16(al1, B0hh[2][1], acch);
        acch = MFMA16(ah0, B0hl[2][0], acch); acch = MFMA16(ah1, B0hl[2][1], acch);

#pragma unroll
        for (int i = 0; i < 4; ++i) {
            const float rr = sigm(accr[i]);
            const float zz = sigm(accz[i]);
            const float nn = tanh_(acci[i] + rr * acch[i]);
            const float hv = (1.f - zz) * nn + zz * hold[i];
            const int r = q * 4 + i;
            const int ix = r * 64 + (jj ^ ((r & 7) << 3));
            const unsigned short hi = f2bf(hv);
            h0h[buf ^ 1][ix] = hi;
            h0l[buf ^ 1][ix] = f2bf(hv - bf2f(hi));
        }
        __syncthreads();

        // ======================= layer 1 =======================
        short8 gh0_ = *(const short8*)&h0h[buf ^ 1][swzA0];
        short8 gh1_ = *(const short8*)&h0h[buf ^ 1][swzA1];
        short8 gl0_ = *(const short8*)&h0l[buf ^ 1][swzA0];
        short8 gl1_ = *(const short8*)&h0l[buf ^ 1][swzA1];
        short8 hh0_ = *(const short8*)&h1h[buf][swzA0];
        short8 hh1_ = *(const short8*)&h1h[buf][swzA1];
        short8 hl0_ = *(const short8*)&h1l[buf][swzA0];
        short8 hl1_ = *(const short8*)&h1l[buf][swzA1];

        float hold1[4];
#pragma unroll
        for (int i = 0; i < 4; ++i) {
            const int r = q * 4 + i;
            const int ix = r * 64 + (jj ^ ((r & 7) << 3));
            hold1[i] = bf2f(h1h[buf][ix]) + bf2f(h1l[buf][ix]);
        }

        f32x4 accr1 = {br1, br1, br1, br1};
        f32x4 accz1 = {bz1, bz1, bz1, bz1};
        f32x4 acci1 = {bi1, bi1, bi1, bi1};
        f32x4 acch1 = {bh1, bh1, bh1, bh1};

        accr1 = MFMA16(gh0_, B1ih[0][0], accr1); accr1 = MFMA16(gh1_, B1ih[0][1], accr1);
        accr1 = MFMA16(gl0_, B1ih[0][0], accr1); accr1 = MFMA16(gl1_, B1ih[0][1], accr1);
        accr1 = MFMA16(gh0_, B1il[0][0], accr1); accr1 = MFMA16(gh1_, B1il[0][1], accr1);
        accr1 = MFMA16(hh0_, B1hh[0][0], accr1); accr1 = MFMA16(hh1_, B1hh[0][1], accr1);
        accr1 = MFMA16(hl0_, B1hh[0][0], accr1); accr1 = MFMA16(hl1_, B1hh[0][1], accr1);
        accr1 = MFMA16(hh0_, B1hl[0][0], accr1); accr1 = MFMA16(hh1_, B1hl[0][1], accr1);

        accz1 = MFMA16(gh0_, B1ih[1][0], accz1); accz1 = MFMA16(gh1_, B1ih[1][1], accz1);
        accz1 = MFMA16(gl0_, B1ih[1][0], accz1); accz1 = MFMA16(gl1_, B1ih[1][1], accz1);
        accz1 = MFMA16(gh0_, B1il[1][0], accz1); accz1 = MFMA16(gh1_, B1il[1][1], accz1);
        accz1 = MFMA16(hh0_, B1hh[1][0], accz1); accz1 = MFMA16(hh1_, B1hh[1][1], accz1);
        accz1 = MFMA16(hl0_, B1hh[1][0], accz1); accz1 = MFMA16(hl1_, B1hh[1][1], accz1);
        accz1 = MFMA16(hh0_, B1hl[1][0], accz1); accz1 = MFMA16(hh1_, B1hl[1][1], accz1);

        acci1 = MFMA16(gh0_, B1ih[2][0], acci1); acci1 = MFMA16(gh1_, B1ih[2][1], acci1);
        acci1 = MFMA16(gl0_, B1ih[2][0], acci1); acci1 = MFMA16(gl1_, B1ih[2][1], acci1);
        acci1 = MFMA16(gh0_, B1il[2][0], acci1); acci1 = MFMA16(gh1_, B1il[2][1], acci1);

        acch1 = MFMA16(hh0_, B1hh[2][0], acch1); acch1 = MFMA16(hh1_, B1hh[2][1], acch1);
        acch1 = MFMA16(hl0_, B1hh[2][0], acch1); acch1 = MFMA16(hl1_, B1hh[2][1], acch1);
        acch1 = MFMA16(hh0_, B1hl[2][0], acch1); acch1 = MFMA16(hh1_, B1hl[2][1], acch1);

#pragma unroll
        for (int i = 0; i < 4; ++i) {
            const float rr = sigm(accr1[i]);
            const float zz = sigm(accz1[i]);
            const float nn = tanh_(acci1[i] + rr * acch1[i]);
            const float hv = (1.f - zz) * nn + zz * hold1[i];
            const int r = q * 4 + i;
            const int ix = r * 64 + (jj ^ ((r & 7) << 3));
            const unsigned short hi = f2bf(hv);
            h1h[buf ^ 1][ix] = hi;
            h1l[buf ^ 1][ix] = f2bf(hv - bf2f(hi));
            if (t == 59 && q == 0)
                xhid[((size_t)blockIdx.x * 4 + i) * 64 + jj] = hv;
        }
        __syncthreads();
        buf ^= 1;
    }
}

// ============================================================================
// Kernel 2: ai[n] = x_hidden[n] . W1 ; aj[n] = x_hidden[n] . W2
// ============================================================================
__global__ void aij_kernel(const float* __restrict__ xh, const float* __restrict__ W,
                           float* __restrict__ ai, float* __restrict__ aj) {
    const int n = blockIdx.x * 256 + threadIdx.x;
    const float* row = xh + (size_t)n * 64;
    float a1 = 0.f, a2 = 0.f;
#pragma unroll
    for (int k = 0; k < 64; k += 4) {
        const f32x4 v = *(const f32x4*)(row + k);
#pragma unroll
        for (int u = 0; u < 4; ++u) {
            a1 += v[u] * W[k + u];
            a2 += v[u] * W[64 + k + u];
        }
    }
    ai[n] = a1;
    aj[n] = a2;
}

// ============================================================================
// Kernel 3: fused relation pass. 256 blocks x 8 rows each.
// Streams relation_matrix once (335 MB -> HBM-bound), builds masked leaky
// scores in LDS, softmax (1/sum folded into epilogue), p @ x_hidden in fp32,
// then final fc -> out.
// ============================================================================
__launch_bounds__(256, 2)
__global__ void rel_kernel(const float* __restrict__ rel, const float* __restrict__ xh,
                           const float* __restrict__ ai, const float* __restrict__ aj,
                           const float* __restrict__ W, const float* __restrict__ bptr,
                           const float* __restrict__ fcw, const float* __restrict__ fcb,
                           float* __restrict__ out) {
    __shared__ float sc[8][2056];
    const int tid = threadIdx.x;
    const int i0  = blockIdx.x * 8;

    float w3[20];
#pragma unroll
    for (int r = 0; r < 20; ++r) w3[r] = W[128 + r];
    float aiv[8];
#pragma unroll
    for (int il = 0; il < 8; ++il) aiv[il] = ai[i0 + il];
    const float bb = bptr[0];

    // phase A: scores
    for (int jc = 0; jc < 8; ++jc) {
        const int j = tid + jc * 256;
        const float ajv = aj[j];
#pragma unroll
        for (int il = 0; il < 8; ++il) {
            const float* rp = rel + ((size_t)(i0 + il) * 2048 + j) * 20;
            float arv = 0.f, ms = 0.f;
#pragma unroll
            for (int r4 = 0; r4 < 5; ++r4) {
                const f32x4 v = *(const f32x4*)(rp + r4 * 4);
                arv += v[0] * w3[r4 * 4] + v[1] * w3[r4 * 4 + 1]
                     + v[2] * w3[r4 * 4 + 2] + v[3] * w3[r4 * 4 + 3];
                ms += v[0] + v[1] + v[2] + v[3];
            }
            float wv = aiv[il] + ajv + arv + bb;
            wv = (wv >= 0.f) ? wv : 0.01f * wv;
            sc[il][j] = (ms != 0.f) ? wv : 0.f;
        }
    }
    __syncthreads();

    // phase B: row softmax (32 threads per row)
    const int il = tid >> 5;
    const int c2 = tid & 31;
    float mx = -1e30f;
    for (int m = 0; m < 64; ++m) mx = fmaxf(mx, sc[il][c2 + 32 * m]);
#pragma unroll
    for (int d = 1; d < 32; d <<= 1) mx = fmaxf(mx, __shfl_xor(mx, d, 64));
    float sm = 0.f;
    for (int m = 0; m < 64; ++m) {
        const int k = c2 + 32 * m;
        const float e = __expf(sc[il][k] - mx);
        sc[il][k] = e;
        sm += e;
    }
#pragma unroll
    for (int d = 1; d < 32; d <<= 1) sm += __shfl_xor(sm, d, 64);
    const float rinv = 1.f / sm;
    __syncthreads();

    // phase C: hidden = p @ x_hidden (unnormalized; scale by rinv at the end)
    const int cc = c2 * 2;
    float acc0 = 0.f, acc1 = 0.f;
    for (int k = 0; k < 2048; k += 2) {
        const float e0 = sc[il][k];
        const float e1 = sc[il][k + 1];
        const float2 v0 = *(const float2*)(xh + (size_t)k * 64 + cc);
        const float2 v1 = *(const float2*)(xh + (size_t)(k + 1) * 64 + cc);
        acc0 += e0 * v0.x + e1 * v1.x;
        acc1 += e0 * v0.y + e1 * v1.y;
    }

    // phase D: pred = (hidden + x_hidden) . fc_w + fc_b
    const int gi = i0 + il;
    const float h0v = acc0 * rinv + xh[(size_t)gi * 64 + cc];
    const float h1v = acc1 * rinv + xh[(size_t)gi * 64 + cc + 1];
    float p = h0v * fcw[cc] + h1v * fcw[cc + 1];
#pragma unroll
    for (int d = 1; d < 32; d <<= 1) p += __shfl_xor(p, d, 64);
    if (c2 == 0) out[gi] = p + fcb[0];
}

// ============================================================================
extern "C" void kernel_launch(void* const* d_in, const int* in_sizes, int n_in,
                              void* d_out, int out_size, void* d_ws, size_t ws_size,
                              hipStream_t stream) {
    const float* x    = (const float*)d_in[0];
    const float* rel  = (const float*)d_in[1];
    const float* Wih0 = (const float*)d_in[2];
    const float* Whh0 = (const float*)d_in[3];
    const float* bih0 = (const float*)d_in[4];
    const float* bhh0 = (const float*)d_in[5];
    const float* Wih1 = (const float*)d_in[6];
    const float* Whh1 = (const float*)d_in[7];
    const float* bih1 = (const float*)d_in[8];
    const float* bhh1 = (const float*)d_in[9];
    const float* W    = (const float*)d_in[10];
    const float* b    = (const float*)d_in[11];
    const float* fcw  = (const float*)d_in[12];
    const float* fcb  = (const float*)d_in[13];
    float* out = (float*)d_out;

    float* xh = (float*)d_ws;          // 2048*64 fp32
    float* ai = xh + 2048 * 64;        // 2048
    float* aj = ai + 2048;             // 2048

    gru_kernel<<<512, 256, 0, stream>>>(x, Wih0, Whh0, bih0, bhh0,
                                        Wih1, Whh1, bih1, bhh1, xh);
    aij_kernel<<<8, 256, 0, stream>>>(xh, W, ai, aj);
    rel_kernel<<<256, 256, 0, stream>>>(rel, xh, ai, aj, W, b, fcw, fcb, out);
}

// Round 2
// 407.097 us; speedup vs baseline: 2.6092x; 2.6092x over previous
//
#include <hip/hip_runtime.h>
#include <cstddef>

typedef __attribute__((ext_vector_type(8))) short short8;
typedef __attribute__((ext_vector_type(4))) float f32x4;

#define MFMA16(a, b, c) __builtin_amdgcn_mfma_f32_16x16x32_bf16((a), (b), (c), 0, 0, 0)

__device__ __forceinline__ unsigned short f2bf(float f) {
    unsigned u = __float_as_uint(f);
    u = (u + 0x7fffu + ((u >> 16) & 1u)) >> 16;
    return (unsigned short)u;
}
__device__ __forceinline__ float bf2f(unsigned short s) {
    return __uint_as_float(((unsigned)s) << 16);
}
__device__ __forceinline__ float sigm(float v) { return 1.f / (1.f + __expf(-v)); }
__device__ __forceinline__ float tanh_(float v) {
    float a = fabsf(v);
    float e = __expf(-2.f * a);
    float t = (1.f - e) / (1.f + e);
    return v < 0.f ? -t : t;
}

// ============================================================================
// Kernel 1: fused 2-layer GRU over T=60 steps.
// __launch_bounds__(256,2): VGPR cap 256 (need ~240 for the 39 short8 weight
// fragments + accumulators). Without this the compiler allocated 64 VGPRs and
// spilled every fragment to scratch -> 2.1 GB/dispatch of scratch traffic.
// 2 blocks/CU at <=256 VGPR.
// ============================================================================
__launch_bounds__(256, 2)
__global__ void gru_kernel(const float* __restrict__ x,
                           const float* __restrict__ Wih0, const float* __restrict__ Whh0,
                           const float* __restrict__ bih0, const float* __restrict__ bhh0,
                           const float* __restrict__ Wih1, const float* __restrict__ Whh1,
                           const float* __restrict__ bih1, const float* __restrict__ bhh1,
                           float* __restrict__ xhid) {
    __shared__ __align__(16) float xs[4 * 360];
    __shared__ __align__(16) unsigned short h0h[2][1024], h0l[2][1024];
    __shared__ __align__(16) unsigned short h1h[2][1024], h1l[2][1024];

    const int tid  = threadIdx.x;
    const int w    = tid >> 6;
    const int lane = tid & 63;
    const int c    = lane & 15;   // A row / C col
    const int q    = lane >> 4;   // quarter
    const int jj   = w * 16 + c;  // hidden unit column this lane produces

    {
        const float* xsrc = x + (size_t)blockIdx.x * 4 * 360;
        for (int i = tid; i < 1440; i += 256) xs[i] = xsrc[i];
        for (int i = tid; i < 1024; i += 256) {
            h0h[0][i] = 0; h0l[0][i] = 0; h1h[0][i] = 0; h1l[0][i] = 0;
        }
    }

    // ---- static per-wave B fragments (registers) ----
    short8 B0hh[3][2], B0hl[3][2];   // layer0 Whh  hi/lo  [gate][ktile]
    short8 B1ih[3][2], B1il[3][2];   // layer1 Wih  hi/lo
    short8 B1hh[3][2], B1hl[3][2];   // layer1 Whh  hi/lo
    short8 B0c[3];                   // layer0 Wih K-concat [Whi|Whi|Wlo]

#pragma unroll
    for (int g = 0; g < 3; ++g) {
        const int o = g * 64 + jj;
#pragma unroll
        for (int kt = 0; kt < 2; ++kt) {
            const int k0 = kt * 32 + q * 8;
#pragma unroll
            for (int e = 0; e < 8; ++e) {
                float v; unsigned short hi;
                v = Whh0[o * 64 + k0 + e]; hi = f2bf(v);
                B0hh[g][kt][e] = (short)hi; B0hl[g][kt][e] = (short)f2bf(v - bf2f(hi));
                v = Wih1[o * 64 + k0 + e]; hi = f2bf(v);
                B1ih[g][kt][e] = (short)hi; B1il[g][kt][e] = (short)f2bf(v - bf2f(hi));
                v = Whh1[o * 64 + k0 + e]; hi = f2bf(v);
                B1hh[g][kt][e] = (short)hi; B1hl[g][kt][e] = (short)f2bf(v - bf2f(hi));
            }
        }
#pragma unroll
        for (int e = 0; e < 8; ++e) {
            const int ks = q * 8 + e;
            unsigned short bv = 0;
            if (ks < 6)       bv = f2bf(Wih0[o * 6 + ks]);
            else if (ks < 12) bv = f2bf(Wih0[o * 6 + ks - 6]);
            else if (ks < 18) {
                const float v = Wih0[o * 6 + ks - 12];
                const unsigned short hi = f2bf(v);
                bv = f2bf(v - bf2f(hi));
            }
            B0c[g][e] = (short)bv;
        }
    }

    const float br0 = bih0[jj] + bhh0[jj];
    const float bz0 = bih0[64 + jj] + bhh0[64 + jj];
    const float bi0 = bih0[128 + jj];
    const float bh0 = bhh0[128 + jj];
    const float br1 = bih1[jj] + bhh1[jj];
    const float bz1 = bih1[64 + jj] + bhh1[64 + jj];
    const float bi1 = bih1[128 + jj];
    const float bh1 = bhh1[128 + jj];

    __syncthreads();

    const int ka = q * 8;
    const int swzA0 = c * 64 + (ka ^ ((c & 7) << 3));         // ktile0 frag addr
    const int swzA1 = c * 64 + ((32 + ka) ^ ((c & 7) << 3));  // ktile1 frag addr

    int buf = 0;
    for (int t = 0; t < 60; ++t) {
        // ======================= layer 0 =======================
        short8 ah0 = *(const short8*)&h0h[buf][swzA0];
        short8 ah1 = *(const short8*)&h0h[buf][swzA1];
        short8 al0 = *(const short8*)&h0l[buf][swzA0];
        short8 al1 = *(const short8*)&h0l[buf][swzA1];

        // x K-concat A-fragment [xhi(6)|xlo(6)|xhi(6)|0...]
        const int sx = (c & 3) * 360;
        const float x0 = xs[sx + t],       x1 = xs[sx + 60 + t],  x2 = xs[sx + 120 + t];
        const float x3 = xs[sx + 180 + t], x4 = xs[sx + 240 + t], x5 = xs[sx + 300 + t];
        const unsigned short H0 = f2bf(x0), H1 = f2bf(x1), H2 = f2bf(x2);
        const unsigned short H3 = f2bf(x3), H4 = f2bf(x4), H5 = f2bf(x5);
        const unsigned short L0 = f2bf(x0 - bf2f(H0)), L1 = f2bf(x1 - bf2f(H1));
        const unsigned short L2 = f2bf(x2 - bf2f(H2)), L3 = f2bf(x3 - bf2f(H3));
        const unsigned short L4 = f2bf(x4 - bf2f(H4)), L5 = f2bf(x5 - bf2f(H5));
        short8 ax;
        if (q == 0) {
            ax[0]=(short)H0; ax[1]=(short)H1; ax[2]=(short)H2; ax[3]=(short)H3;
            ax[4]=(short)H4; ax[5]=(short)H5; ax[6]=(short)L0; ax[7]=(short)L1;
        } else if (q == 1) {
            ax[0]=(short)L2; ax[1]=(short)L3; ax[2]=(short)L4; ax[3]=(short)L5;
            ax[4]=(short)H0; ax[5]=(short)H1; ax[6]=(short)H2; ax[7]=(short)H3;
        } else if (q == 2) {
            ax[0]=(short)H4; ax[1]=(short)H5; ax[2]=0; ax[3]=0;
            ax[4]=0; ax[5]=0; ax[6]=0; ax[7]=0;
        } else {
            ax[0]=0; ax[1]=0; ax[2]=0; ax[3]=0; ax[4]=0; ax[5]=0; ax[6]=0; ax[7]=0;
        }

        float hold[4];
#pragma unroll
        for (int i = 0; i < 4; ++i) {
            const int r = q * 4 + i;
            const int ix = r * 64 + (jj ^ ((r & 7) << 3));
            hold[i] = bf2f(h0h[buf][ix]) + bf2f(h0l[buf][ix]);
        }

        f32x4 accr = {br0, br0, br0, br0};
        f32x4 accz = {bz0, bz0, bz0, bz0};
        f32x4 acci = {bi0, bi0, bi0, bi0};
        f32x4 acch = {bh0, bh0, bh0, bh0};

        accr = MFMA16(ah0, B0hh[0][0], accr); accr = MFMA16(ah1, B0hh[0][1], accr);
        accr = MFMA16(al0, B0hh[0][0], accr); accr = MFMA16(al1, B0hh[0][1], accr);
        accr = MFMA16(ah0, B0hl[0][0], accr); accr = MFMA16(ah1, B0hl[0][1], accr);
        accr = MFMA16(ax, B0c[0], accr);

        accz = MFMA16(ah0, B0hh[1][0], accz); accz = MFMA16(ah1, B0hh[1][1], accz);
        accz = MFMA16(al0, B0hh[1][0], accz); accz = MFMA16(al1, B0hh[1][1], accz);
        accz = MFMA16(ah0, B0hl[1][0], accz); accz = MFMA16(ah1, B0hl[1][1], accz);
        accz = MFMA16(ax, B0c[1], accz);

        acci = MFMA16(ax, B0c[2], acci);

        acch = MFMA16(ah0, B0hh[2][0], acch); acch = MFMA16(ah1, B0hh[2][1], acch);
        acch = MFMA16(al0, B0hh[2][0], acch); acch = MFMA16(al1, B0hh[2][1], acch);
        acch = MFMA16(ah0, B0hl[2][0], acch); acch = MFMA16(ah1, B0hl[2][1], acch);

#pragma unroll
        for (int i = 0; i < 4; ++i) {
            const float rr = sigm(accr[i]);
            const float zz = sigm(accz[i]);
            const float nn = tanh_(acci[i] + rr * acch[i]);
            const float hv = (1.f - zz) * nn + zz * hold[i];
            const int r = q * 4 + i;
            const int ix = r * 64 + (jj ^ ((r & 7) << 3));
            const unsigned short hi = f2bf(hv);
            h0h[buf ^ 1][ix] = hi;
            h0l[buf ^ 1][ix] = f2bf(hv - bf2f(hi));
        }
        __syncthreads();

        // ======================= layer 1 =======================
        short8 gh0_ = *(const short8*)&h0h[buf ^ 1][swzA0];
        short8 gh1_ = *(const short8*)&h0h[buf ^ 1][swzA1];
        short8 gl0_ = *(const short8*)&h0l[buf ^ 1][swzA0];
        short8 gl1_ = *(const short8*)&h0l[buf ^ 1][swzA1];
        short8 hh0_ = *(const short8*)&h1h[buf][swzA0];
        short8 hh1_ = *(const short8*)&h1h[buf][swzA1];
        short8 hl0_ = *(const short8*)&h1l[buf][swzA0];
        short8 hl1_ = *(const short8*)&h1l[buf][swzA1];

        float hold1[4];
#pragma unroll
        for (int i = 0; i < 4; ++i) {
            const int r = q * 4 + i;
            const int ix = r * 64 + (jj ^ ((r & 7) << 3));
            hold1[i] = bf2f(h1h[buf][ix]) + bf2f(h1l[buf][ix]);
        }

        f32x4 accr1 = {br1, br1, br1, br1};
        f32x4 accz1 = {bz1, bz1, bz1, bz1};
        f32x4 acci1 = {bi1, bi1, bi1, bi1};
        f32x4 acch1 = {bh1, bh1, bh1, bh1};

        accr1 = MFMA16(gh0_, B1ih[0][0], accr1); accr1 = MFMA16(gh1_, B1ih[0][1], accr1);
        accr1 = MFMA16(gl0_, B1ih[0][0], accr1); accr1 = MFMA16(gl1_, B1ih[0][1], accr1);
        accr1 = MFMA16(gh0_, B1il[0][0], accr1); accr1 = MFMA16(gh1_, B1il[0][1], accr1);
        accr1 = MFMA16(hh0_, B1hh[0][0], accr1); accr1 = MFMA16(hh1_, B1hh[0][1], accr1);
        accr1 = MFMA16(hl0_, B1hh[0][0], accr1); accr1 = MFMA16(hl1_, B1hh[0][1], accr1);
        accr1 = MFMA16(hh0_, B1hl[0][0], accr1); accr1 = MFMA16(hh1_, B1hl[0][1], accr1);

        accz1 = MFMA16(gh0_, B1ih[1][0], accz1); accz1 = MFMA16(gh1_, B1ih[1][1], accz1);
        accz1 = MFMA16(gl0_, B1ih[1][0], accz1); accz1 = MFMA16(gl1_, B1ih[1][1], accz1);
        accz1 = MFMA16(gh0_, B1il[1][0], accz1); accz1 = MFMA16(gh1_, B1il[1][1], accz1);
        accz1 = MFMA16(hh0_, B1hh[1][0], accz1); accz1 = MFMA16(hh1_, B1hh[1][1], accz1);
        accz1 = MFMA16(hl0_, B1hh[1][0], accz1); accz1 = MFMA16(hl1_, B1hh[1][1], accz1);
        accz1 = MFMA16(hh0_, B1hl[1][0], accz1); accz1 = MFMA16(hh1_, B1hl[1][1], accz1);

        acci1 = MFMA16(gh0_, B1ih[2][0], acci1); acci1 = MFMA16(gh1_, B1ih[2][1], acci1);
        acci1 = MFMA16(gl0_, B1ih[2][0], acci1); acci1 = MFMA16(gl1_, B1ih[2][1], acci1);
        acci1 = MFMA16(gh0_, B1il[2][0], acci1); acci1 = MFMA16(gh1_, B1il[2][1], acci1);

        acch1 = MFMA16(hh0_, B1hh[2][0], acch1); acch1 = MFMA16(hh1_, B1hh[2][1], acch1);
        acch1 = MFMA16(hl0_, B1hh[2][0], acch1); acch1 = MFMA16(hl1_, B1hh[2][1], acch1);
        acch1 = MFMA16(hh0_, B1hl[2][0], acch1); acch1 = MFMA16(hh1_, B1hl[2][1], acch1);

#pragma unroll
        for (int i = 0; i < 4; ++i) {
            const float rr = sigm(accr1[i]);
            const float zz = sigm(accz1[i]);
            const float nn = tanh_(acci1[i] + rr * acch1[i]);
            const float hv = (1.f - zz) * nn + zz * hold1[i];
            const int r = q * 4 + i;
            const int ix = r * 64 + (jj ^ ((r & 7) << 3));
            const unsigned short hi = f2bf(hv);
            h1h[buf ^ 1][ix] = hi;
            h1l[buf ^ 1][ix] = f2bf(hv - bf2f(hi));
            if (t == 59 && q == 0)
                xhid[((size_t)blockIdx.x * 4 + i) * 64 + jj] = hv;
        }
        __syncthreads();
        buf ^= 1;
    }
}

// ============================================================================
// Kernel 2: ai[n] = x_hidden[n] . W1 ; aj[n] = x_hidden[n] . W2
// ============================================================================
__global__ void aij_kernel(const float* __restrict__ xh, const float* __restrict__ W,
                           float* __restrict__ ai, float* __restrict__ aj) {
    const int n = blockIdx.x * 256 + threadIdx.x;
    const float* row = xh + (size_t)n * 64;
    float a1 = 0.f, a2 = 0.f;
#pragma unroll
    for (int k = 0; k < 64; k += 4) {
        const f32x4 v = *(const f32x4*)(row + k);
#pragma unroll
        for (int u = 0; u < 4; ++u) {
            a1 += v[u] * W[k + u];
            a2 += v[u] * W[64 + k + u];
        }
    }
    ai[n] = a1;
    aj[n] = a2;
}

// ============================================================================
// Kernel 3: fused relation pass. 256 blocks x 1024 threads, 8 rows per block.
// 1024 threads -> 4 waves/SIMD (VGPR<=128) so enough loads in flight to cover
// HBM latency in the 335 MB stream (phase A). Phase C strip-mapped: each
// thread owns one xh column + one 128-wide K strip, applies it to all 8 rows
// -> xh read ONCE per block (512 KB L2, not 4 MB) and sc reads are
// wave-uniform broadcasts.
// ============================================================================
__launch_bounds__(1024, 4)
__global__ void rel_kernel(const float* __restrict__ rel, const float* __restrict__ xh,
                           const float* __restrict__ ai, const float* __restrict__ aj,
                           const float* __restrict__ W, const float* __restrict__ bptr,
                           const float* __restrict__ fcw, const float* __restrict__ fcb,
                           float* __restrict__ out) {
    __shared__ float sc[8][2056];
    __shared__ float hidpart[16][8][64];
    __shared__ float redm[8][2], reds[8][2];
    __shared__ float rinv_s[8];

    const int tid = threadIdx.x;
    const int i0  = blockIdx.x * 8;

    float w3[20];
#pragma unroll
    for (int r = 0; r < 20; ++r) w3[r] = W[128 + r];
    float aiv[8];
#pragma unroll
    for (int il = 0; il < 8; ++il) aiv[il] = ai[i0 + il];
    const float bb = bptr[0];

    // ---------------- phase A: masked leaky scores ----------------
#pragma unroll
    for (int jc = 0; jc < 2; ++jc) {
        const int j = tid + jc * 1024;
        const float ajv = aj[j];
#pragma unroll
        for (int il = 0; il < 8; ++il) {
            const float* rp = rel + ((size_t)(i0 + il) * 2048 + j) * 20;
            float arv = 0.f, ms = 0.f;
#pragma unroll
            for (int r4 = 0; r4 < 5; ++r4) {
                const f32x4 v = *(const f32x4*)(rp + r4 * 4);
                arv += v[0] * w3[r4 * 4] + v[1] * w3[r4 * 4 + 1]
                     + v[2] * w3[r4 * 4 + 2] + v[3] * w3[r4 * 4 + 3];
                ms += v[0] + v[1] + v[2] + v[3];
            }
            float wv = aiv[il] + ajv + arv + bb;
            wv = (wv >= 0.f) ? wv : 0.01f * wv;
            sc[il][j] = (ms != 0.f) ? wv : 0.f;
        }
    }
    __syncthreads();

    // ---------------- phase B: row softmax (128 threads / row) ----------------
    const int row = tid >> 7;    // 0..7
    const int c7  = tid & 127;   // 0..127
    const int wh  = (tid >> 6) & 1;  // which wave within the row's 128 threads

    float mx = -1e30f;
#pragma unroll
    for (int m = 0; m < 16; ++m) mx = fmaxf(mx, sc[row][c7 + 128 * m]);
#pragma unroll
    for (int d = 1; d < 64; d <<= 1) mx = fmaxf(mx, __shfl_xor(mx, d, 64));
    if ((tid & 63) == 0) redm[row][wh] = mx;
    __syncthreads();
    mx = fmaxf(redm[row][0], redm[row][1]);

    float sm = 0.f;
#pragma unroll
    for (int m = 0; m < 16; ++m) {
        const int k = c7 + 128 * m;
        const float e = __expf(sc[row][k] - mx);
        sc[row][k] = e;
        sm += e;
    }
#pragma unroll
    for (int d = 1; d < 64; d <<= 1) sm += __shfl_xor(sm, d, 64);
    if ((tid & 63) == 0) reds[row][wh] = sm;
    __syncthreads();
    if ((tid & 127) == 0) rinv_s[row] = 1.f / (reds[row][0] + reds[row][1]);

    // ---------------- phase C: hidden = p @ x_hidden (strip-mapped) -----------
    const int col   = tid & 63;          // wave-lane = column -> coalesced xh
    const int strip = tid >> 6;          // wave id = K strip (wave-uniform)
    const int k0s   = strip * 128;

    float acc[8] = {0.f, 0.f, 0.f, 0.f, 0.f, 0.f, 0.f, 0.f};
    for (int k = 0; k < 128; k += 4) {
        const float v0 = xh[(size_t)(k0s + k) * 64 + col];
        const float v1 = xh[(size_t)(k0s + k + 1) * 64 + col];
        const float v2 = xh[(size_t)(k0s + k + 2) * 64 + col];
        const float v3 = xh[(size_t)(k0s + k + 3) * 64 + col];
#pragma unroll
        for (int il = 0; il < 8; ++il) {
            const f32x4 e = *(const f32x4*)&sc[il][k0s + k];
            acc[il] += e[0] * v0 + e[1] * v1 + e[2] * v2 + e[3] * v3;
        }
    }
#pragma unroll
    for (int il = 0; il < 8; ++il) hidpart[strip][il][col] = acc[il];
    __syncthreads();

    // ---------------- phase D: reduce strips + final fc ----------------
    if (tid < 512) {
        const int r2 = tid >> 6;   // row, one wave per row
        const int cl = tid & 63;   // column
        float hsum = 0.f;
#pragma unroll
        for (int s = 0; s < 16; ++s) hsum += hidpart[s][r2][cl];
        const float h = hsum * rinv_s[r2] + xh[(size_t)(i0 + r2) * 64 + cl];
        float p = h * fcw[cl];
#pragma unroll
        for (int d = 1; d < 64; d <<= 1) p += __shfl_xor(p, d, 64);
        if (cl == 0) out[i0 + r2] = p + fcb[0];
    }
}

// ============================================================================
extern "C" void kernel_launch(void* const* d_in, const int* in_sizes, int n_in,
                              void* d_out, int out_size, void* d_ws, size_t ws_size,
                              hipStream_t stream) {
    const float* x    = (const float*)d_in[0];
    const float* rel  = (const float*)d_in[1];
    const float* Wih0 = (const float*)d_in[2];
    const float* Whh0 = (const float*)d_in[3];
    const float* bih0 = (const float*)d_in[4];
    const float* bhh0 = (const float*)d_in[5];
    const float* Wih1 = (const float*)d_in[6];
    const float* Whh1 = (const float*)d_in[7];
    const float* bih1 = (const float*)d_in[8];
    const float* bhh1 = (const float*)d_in[9];
    const float* W    = (const float*)d_in[10];
    const float* b    = (const float*)d_in[11];
    const float* fcw  = (const float*)d_in[12];
    const float* fcb  = (const float*)d_in[13];
    float* out = (float*)d_out;

    float* xh = (float*)d_ws;          // 2048*64 fp32
    float* ai = xh + 2048 * 64;        // 2048
    float* aj = ai + 2048;             // 2048

    gru_kernel<<<512, 256, 0, stream>>>(x, Wih0, Whh0, bih0, bhh0,
                                        Wih1, Whh1, bih1, bhh1, xh);
    aij_kernel<<<8, 256, 0, stream>>>(xh, W, ai, aj);
    rel_kernel<<<256, 1024, 0, stream>>>(rel, xh, ai, aj, W, b, fcw, fcb, out);
}

// Round 3
// 279.610 us; speedup vs baseline: 3.7988x; 1.4559x over previous
//
#include <hip/hip_runtime.h>
#include <cstddef>

typedef __attribute__((ext_vector_type(8))) short short8;
typedef __attribute__((ext_vector_type(4))) float f32x4;

#define MFMA16(a, b, c) __builtin_amdgcn_mfma_f32_16x16x32_bf16((a), (b), (c), 0, 0, 0)

__device__ __forceinline__ unsigned short f2bf(float f) {
    unsigned u = __float_as_uint(f);
    u = (u + 0x7fffu + ((u >> 16) & 1u)) >> 16;
    return (unsigned short)u;
}
__device__ __forceinline__ float bf2f(unsigned short s) {
    return __uint_as_float(((unsigned)s) << 16);
}
__device__ __forceinline__ float sigm(float v) { return 1.f / (1.f + __expf(-v)); }
__device__ __forceinline__ float tanh_(float v) {
    float a = fabsf(v);
    float e = __expf(-2.f * a);
    float t = (1.f - e) / (1.f + e);
    return v < 0.f ? -t : t;
}

// ============================================================================
// Fused 2-layer GRU, layer-pipelined across wave groups.
// 256 blocks x 768 threads (12 waves), M=8 samples/block (tile rows 8-15 dup).
//   G0 (waves 0-3):  layer0 step      h0[i+1] = GRU0(h0[i], x[i])
//   G1 (waves 4-7):  layer1 input-half P1[i]  = Wih1 . h0[i] (+input biases)
//   G2 (waves 8-11): layer1 recur-half + epilogue h1[i-1] = f(P1[i-1], h1[i-2])
// Depth-2 software pipeline, 62 iterations, ONE barrier per iteration.
// Per-wave B-fragments: 12-15 short8 (48-60 VGPR) -> fits arch VGPRs,
// no AGPR shuffling (R2's VALU tax), 3 waves/SIMD.
// Split-bf16 everywhere: W*h ~= Whi*hhi + Whi*hlo + Wlo*hhi.
// ============================================================================
__launch_bounds__(768, 3)
__global__ void gru_kernel(const float* __restrict__ x,
                           const float* __restrict__ Wih0, const float* __restrict__ Whh0,
                           const float* __restrict__ bih0, const float* __restrict__ bhh0,
                           const float* __restrict__ Wih1, const float* __restrict__ Whh1,
                           const float* __restrict__ bih1, const float* __restrict__ bhh1,
                           float* __restrict__ xhid) {
    __shared__ __align__(16) unsigned short h0h[2][1024], h0l[2][1024];
    __shared__ __align__(16) unsigned short h1h[2][1024], h1l[2][1024];
    __shared__ __align__(16) float P1[2][16][195];
    __shared__ __align__(16) short8 axbuf[2400];   // [t][sample][q] stride 40 = t*40+s*5+q

    const int tid  = threadIdx.x;
    const int grp  = tid >> 8;        // 0,1,2
    const int lane = tid & 63;
    const int gw   = (tid >> 6) & 3;  // wave within group
    const int c    = lane & 15;       // A row / C col
    const int q    = lane >> 4;       // quarter
    const int jj   = gw * 16 + c;     // hidden-unit column

    // ---- setup: zero parity-0 states ----
    for (int i = tid; i < 1024; i += 768) {
        h0h[0][i] = 0; h0l[0][i] = 0; h1h[0][i] = 0; h1l[0][i] = 0;
    }
    // ---- precompute x MFMA A-fragments (hi/lo K-concat), once ----
    {
        const float* xb = x + (size_t)blockIdx.x * 8 * 360;
        for (int f = tid; f < 1920; f += 768) {
            const int t = f >> 5, s = (f >> 2) & 7, qq = f & 3;
            unsigned short Hh[6], Ll[6];
#pragma unroll
            for (int d = 0; d < 6; ++d) {
                const float v = xb[s * 360 + d * 60 + t];
                Hh[d] = f2bf(v); Ll[d] = f2bf(v - bf2f(Hh[d]));
            }
            short8 fr;
#pragma unroll
            for (int e = 0; e < 8; ++e) {
                const int k = qq * 8 + e;
                unsigned short u = 0;
                if (k < 6) u = Hh[k];
                else if (k < 12) u = Ll[k - 6];
                else if (k < 18) u = Hh[k - 12];
                fr[e] = (short)u;
            }
            axbuf[t * 40 + s * 5 + qq] = fr;
        }
    }

    const int ka    = q * 8;
    const int swzA0 = c * 64 + (ka ^ ((c & 7) << 3));
    const int swzA1 = c * 64 + ((32 + ka) ^ ((c & 7) << 3));

    __syncthreads();

    if (grp == 0) {
        // ================= G0: layer 0 =================
        short8 Bhh[3][2], Bhl[3][2], Bc[3];
#pragma unroll
        for (int g = 0; g < 3; ++g) {
            const int o = g * 64 + jj;
#pragma unroll
            for (int kt = 0; kt < 2; ++kt) {
                const int k0 = kt * 32 + q * 8;
#pragma unroll
                for (int e = 0; e < 8; ++e) {
                    const float v = Whh0[o * 64 + k0 + e];
                    const unsigned short hi = f2bf(v);
                    Bhh[g][kt][e] = (short)hi; Bhl[g][kt][e] = (short)f2bf(v - bf2f(hi));
                }
            }
#pragma unroll
            for (int e = 0; e < 8; ++e) {
                const int ks = q * 8 + e;
                unsigned short bv = 0;
                if (ks < 6)       bv = f2bf(Wih0[o * 6 + ks]);
                else if (ks < 12) bv = f2bf(Wih0[o * 6 + ks - 6]);
                else if (ks < 18) {
                    const float v = Wih0[o * 6 + ks - 12];
                    const unsigned short hi = f2bf(v);
                    bv = f2bf(v - bf2f(hi));
                }
                Bc[g][e] = (short)bv;
            }
        }
        const float br = bih0[jj] + bhh0[jj];
        const float bz = bih0[64 + jj] + bhh0[64 + jj];
        const float bi = bih0[128 + jj];
        const float bh = bhh0[128 + jj];
        float hreg[4] = {0.f, 0.f, 0.f, 0.f};

        for (int it = 0; it < 62; ++it) {
            if (it < 60) {
                const int par = it & 1;
                const short8 ah0 = *(const short8*)&h0h[par][swzA0];
                const short8 ah1 = *(const short8*)&h0h[par][swzA1];
                const short8 al0 = *(const short8*)&h0l[par][swzA0];
                const short8 al1 = *(const short8*)&h0l[par][swzA1];
                const short8 ax  = axbuf[it * 40 + (c & 7) * 5 + q];

                f32x4 accr = {br, br, br, br};
                f32x4 accz = {bz, bz, bz, bz};
                f32x4 acci = {bi, bi, bi, bi};
                f32x4 acch = {bh, bh, bh, bh};

                accr = MFMA16(ah0, Bhh[0][0], accr); accr = MFMA16(ah1, Bhh[0][1], accr);
                accr = MFMA16(al0, Bhh[0][0], accr); accr = MFMA16(al1, Bhh[0][1], accr);
                accr = MFMA16(ah0, Bhl[0][0], accr); accr = MFMA16(ah1, Bhl[0][1], accr);
                accr = MFMA16(ax, Bc[0], accr);

                accz = MFMA16(ah0, Bhh[1][0], accz); accz = MFMA16(ah1, Bhh[1][1], accz);
                accz = MFMA16(al0, Bhh[1][0], accz); accz = MFMA16(al1, Bhh[1][1], accz);
                accz = MFMA16(ah0, Bhl[1][0], accz); accz = MFMA16(ah1, Bhl[1][1], accz);
                accz = MFMA16(ax, Bc[1], accz);

                acci = MFMA16(ax, Bc[2], acci);

                acch = MFMA16(ah0, Bhh[2][0], acch); acch = MFMA16(ah1, Bhh[2][1], acch);
                acch = MFMA16(al0, Bhh[2][0], acch); acch = MFMA16(al1, Bhh[2][1], acch);
                acch = MFMA16(ah0, Bhl[2][0], acch); acch = MFMA16(ah1, Bhl[2][1], acch);

#pragma unroll
                for (int i2 = 0; i2 < 4; ++i2) {
                    const float rr = sigm(accr[i2]);
                    const float zz = sigm(accz[i2]);
                    const float nn = tanh_(acci[i2] + rr * acch[i2]);
                    const float hv = (1.f - zz) * nn + zz * hreg[i2];
                    hreg[i2] = hv;
                    const int r  = q * 4 + i2;
                    const int ix = r * 64 + (jj ^ ((r & 7) << 3));
                    const unsigned short hi = f2bf(hv);
                    h0h[par ^ 1][ix] = hi;
                    h0l[par ^ 1][ix] = f2bf(hv - bf2f(hi));
                }
            }
            __syncthreads();
        }
    } else if (grp == 1) {
        // ================= G1: layer 1 input half =================
        short8 Bih[3][2], Bil[3][2];
#pragma unroll
        for (int g = 0; g < 3; ++g) {
            const int o = g * 64 + jj;
#pragma unroll
            for (int kt = 0; kt < 2; ++kt) {
                const int k0 = kt * 32 + q * 8;
#pragma unroll
                for (int e = 0; e < 8; ++e) {
                    const float v = Wih1[o * 64 + k0 + e];
                    const unsigned short hi = f2bf(v);
                    Bih[g][kt][e] = (short)hi; Bil[g][kt][e] = (short)f2bf(v - bf2f(hi));
                }
            }
        }
        const float br = bih1[jj] + bhh1[jj];
        const float bz = bih1[64 + jj] + bhh1[64 + jj];
        const float bi = bih1[128 + jj];

        for (int it = 0; it < 62; ++it) {
            if (it >= 1 && it < 61) {
                const int par = it & 1;
                const short8 gh0 = *(const short8*)&h0h[par][swzA0];
                const short8 gh1 = *(const short8*)&h0h[par][swzA1];
                const short8 gl0 = *(const short8*)&h0l[par][swzA0];
                const short8 gl1 = *(const short8*)&h0l[par][swzA1];

                f32x4 ar = {br, br, br, br};
                f32x4 az = {bz, bz, bz, bz};
                f32x4 an = {bi, bi, bi, bi};

                ar = MFMA16(gh0, Bih[0][0], ar); ar = MFMA16(gh1, Bih[0][1], ar);
                ar = MFMA16(gl0, Bih[0][0], ar); ar = MFMA16(gl1, Bih[0][1], ar);
                ar = MFMA16(gh0, Bil[0][0], ar); ar = MFMA16(gh1, Bil[0][1], ar);

                az = MFMA16(gh0, Bih[1][0], az); az = MFMA16(gh1, Bih[1][1], az);
                az = MFMA16(gl0, Bih[1][0], az); az = MFMA16(gl1, Bih[1][1], az);
                az = MFMA16(gh0, Bil[1][0], az); az = MFMA16(gh1, Bil[1][1], az);

                an = MFMA16(gh0, Bih[2][0], an); an = MFMA16(gh1, Bih[2][1], an);
                an = MFMA16(gl0, Bih[2][0], an); an = MFMA16(gl1, Bih[2][1], an);
                an = MFMA16(gh0, Bil[2][0], an); an = MFMA16(gh1, Bil[2][1], an);

#pragma unroll
                for (int i2 = 0; i2 < 4; ++i2) {
                    const int r = q * 4 + i2;
                    P1[par][r][jj]       = ar[i2];
                    P1[par][r][64 + jj]  = az[i2];
                    P1[par][r][128 + jj] = an[i2];
                }
            }
            __syncthreads();
        }
    } else {
        // ================= G2: layer 1 recurrent half + epilogue =================
        short8 Bhh[3][2], Bhl[3][2];
#pragma unroll
        for (int g = 0; g < 3; ++g) {
            const int o = g * 64 + jj;
#pragma unroll
            for (int kt = 0; kt < 2; ++kt) {
                const int k0 = kt * 32 + q * 8;
#pragma unroll
                for (int e = 0; e < 8; ++e) {
                    const float v = Whh1[o * 64 + k0 + e];
                    const unsigned short hi = f2bf(v);
                    Bhh[g][kt][e] = (short)hi; Bhl[g][kt][e] = (short)f2bf(v - bf2f(hi));
                }
            }
        }
        const float bh = bhh1[128 + jj];
        float hreg[4] = {0.f, 0.f, 0.f, 0.f};

        for (int it = 0; it < 62; ++it) {
            if (it >= 2) {
                const int par = it & 1;
                const short8 hh0 = *(const short8*)&h1h[par][swzA0];
                const short8 hh1_ = *(const short8*)&h1h[par][swzA1];
                const short8 hl0 = *(const short8*)&h1l[par][swzA0];
                const short8 hl1_ = *(const short8*)&h1l[par][swzA1];

                float p1r[4], p1z[4], p1n[4];
#pragma unroll
                for (int i2 = 0; i2 < 4; ++i2) {
                    const int r = q * 4 + i2;
                    p1r[i2] = P1[par ^ 1][r][jj];
                    p1z[i2] = P1[par ^ 1][r][64 + jj];
                    p1n[i2] = P1[par ^ 1][r][128 + jj];
                }

                f32x4 ar  = {p1r[0], p1r[1], p1r[2], p1r[3]};
                f32x4 az  = {p1z[0], p1z[1], p1z[2], p1z[3]};
                f32x4 ahn = {bh, bh, bh, bh};

                ar = MFMA16(hh0, Bhh[0][0], ar); ar = MFMA16(hh1_, Bhh[0][1], ar);
                ar = MFMA16(hl0, Bhh[0][0], ar); ar = MFMA16(hl1_, Bhh[0][1], ar);
                ar = MFMA16(hh0, Bhl[0][0], ar); ar = MFMA16(hh1_, Bhl[0][1], ar);

                az = MFMA16(hh0, Bhh[1][0], az); az = MFMA16(hh1_, Bhh[1][1], az);
                az = MFMA16(hl0, Bhh[1][0], az); az = MFMA16(hl1_, Bhh[1][1], az);
                az = MFMA16(hh0, Bhl[1][0], az); az = MFMA16(hh1_, Bhl[1][1], az);

                ahn = MFMA16(hh0, Bhh[2][0], ahn); ahn = MFMA16(hh1_, Bhh[2][1], ahn);
                ahn = MFMA16(hl0, Bhh[2][0], ahn); ahn = MFMA16(hl1_, Bhh[2][1], ahn);
                ahn = MFMA16(hh0, Bhl[2][0], ahn); ahn = MFMA16(hh1_, Bhl[2][1], ahn);

#pragma unroll
                for (int i2 = 0; i2 < 4; ++i2) {
                    const float rr = sigm(ar[i2]);
                    const float zz = sigm(az[i2]);
                    const float nn = tanh_(p1n[i2] + rr * ahn[i2]);
                    const float hv = (1.f - zz) * nn + zz * hreg[i2];
                    hreg[i2] = hv;
                    const int r  = q * 4 + i2;
                    const int ix = r * 64 + (jj ^ ((r & 7) << 3));
                    const unsigned short hi = f2bf(hv);
                    h1h[par ^ 1][ix] = hi;
                    h1l[par ^ 1][ix] = f2bf(hv - bf2f(hi));
                    if (it == 61 && q < 2)
                        xhid[((size_t)blockIdx.x * 8 + r) * 64 + jj] = hv;
                }
            }
            __syncthreads();
        }
    }
}

// ============================================================================
// Kernel 2: ai[n] = x_hidden[n] . W1 ; aj[n] = x_hidden[n] . W2
// ============================================================================
__global__ void aij_kernel(const float* __restrict__ xh, const float* __restrict__ W,
                           float* __restrict__ ai, float* __restrict__ aj) {
    const int n = blockIdx.x * 256 + threadIdx.x;
    const float* row = xh + (size_t)n * 64;
    float a1 = 0.f, a2 = 0.f;
#pragma unroll
    for (int k = 0; k < 64; k += 4) {
        const f32x4 v = *(const f32x4*)(row + k);
#pragma unroll
        for (int u = 0; u < 4; ++u) {
            a1 += v[u] * W[k + u];
            a2 += v[u] * W[64 + k + u];
        }
    }
    ai[n] = a1;
    aj[n] = a2;
}

// ============================================================================
// Kernel 3: fused relation pass (unchanged from R2 — awaiting its counters).
// ============================================================================
__launch_bounds__(1024, 4)
__global__ void rel_kernel(const float* __restrict__ rel, const float* __restrict__ xh,
                           const float* __restrict__ ai, const float* __restrict__ aj,
                           const float* __restrict__ W, const float* __restrict__ bptr,
                           const float* __restrict__ fcw, const float* __restrict__ fcb,
                           float* __restrict__ out) {
    __shared__ float sc[8][2056];
    __shared__ float hidpart[16][8][64];
    __shared__ float redm[8][2], reds[8][2];
    __shared__ float rinv_s[8];

    const int tid = threadIdx.x;
    const int i0  = blockIdx.x * 8;

    float w3[20];
#pragma unroll
    for (int r = 0; r < 20; ++r) w3[r] = W[128 + r];
    float aiv[8];
#pragma unroll
    for (int il = 0; il < 8; ++il) aiv[il] = ai[i0 + il];
    const float bb = bptr[0];

    // ---------------- phase A: masked leaky scores ----------------
#pragma unroll
    for (int jc = 0; jc < 2; ++jc) {
        const int j = tid + jc * 1024;
        const float ajv = aj[j];
#pragma unroll
        for (int il = 0; il < 8; ++il) {
            const float* rp = rel + ((size_t)(i0 + il) * 2048 + j) * 20;
            float arv = 0.f, ms = 0.f;
#pragma unroll
            for (int r4 = 0; r4 < 5; ++r4) {
                const f32x4 v = *(const f32x4*)(rp + r4 * 4);
                arv += v[0] * w3[r4 * 4] + v[1] * w3[r4 * 4 + 1]
                     + v[2] * w3[r4 * 4 + 2] + v[3] * w3[r4 * 4 + 3];
                ms += v[0] + v[1] + v[2] + v[3];
            }
            float wv = aiv[il] + ajv + arv + bb;
            wv = (wv >= 0.f) ? wv : 0.01f * wv;
            sc[il][j] = (ms != 0.f) ? wv : 0.f;
        }
    }
    __syncthreads();

    // ---------------- phase B: row softmax (128 threads / row) ----------------
    const int row = tid >> 7;
    const int c7  = tid & 127;
    const int wh  = (tid >> 6) & 1;

    float mx = -1e30f;
#pragma unroll
    for (int m = 0; m < 16; ++m) mx = fmaxf(mx, sc[row][c7 + 128 * m]);
#pragma unroll
    for (int d = 1; d < 64; d <<= 1) mx = fmaxf(mx, __shfl_xor(mx, d, 64));
    if ((tid & 63) == 0) redm[row][wh] = mx;
    __syncthreads();
    mx = fmaxf(redm[row][0], redm[row][1]);

    float sm = 0.f;
#pragma unroll
    for (int m = 0; m < 16; ++m) {
        const int k = c7 + 128 * m;
        const float e = __expf(sc[row][k] - mx);
        sc[row][k] = e;
        sm += e;
    }
#pragma unroll
    for (int d = 1; d < 64; d <<= 1) sm += __shfl_xor(sm, d, 64);
    if ((tid & 63) == 0) reds[row][wh] = sm;
    __syncthreads();
    if ((tid & 127) == 0) rinv_s[row] = 1.f / (reds[row][0] + reds[row][1]);

    // ---------------- phase C: hidden = p @ x_hidden (strip-mapped) -----------
    const int col   = tid & 63;
    const int strip = tid >> 6;
    const int k0s   = strip * 128;

    float acc[8] = {0.f, 0.f, 0.f, 0.f, 0.f, 0.f, 0.f, 0.f};
    for (int k = 0; k < 128; k += 4) {
        const float v0 = xh[(size_t)(k0s + k) * 64 + col];
        const float v1 = xh[(size_t)(k0s + k + 1) * 64 + col];
        const float v2 = xh[(size_t)(k0s + k + 2) * 64 + col];
        const float v3 = xh[(size_t)(k0s + k + 3) * 64 + col];
#pragma unroll
        for (int il = 0; il < 8; ++il) {
            const f32x4 e = *(const f32x4*)&sc[il][k0s + k];
            acc[il] += e[0] * v0 + e[1] * v1 + e[2] * v2 + e[3] * v3;
        }
    }
#pragma unroll
    for (int il = 0; il < 8; ++il) hidpart[strip][il][col] = acc[il];
    __syncthreads();

    // ---------------- phase D: reduce strips + final fc ----------------
    if (tid < 512) {
        const int r2 = tid >> 6;
        const int cl = tid & 63;
        float hsum = 0.f;
#pragma unroll
        for (int s = 0; s < 16; ++s) hsum += hidpart[s][r2][cl];
        const float h = hsum * rinv_s[r2] + xh[(size_t)(i0 + r2) * 64 + cl];
        float p = h * fcw[cl];
#pragma unroll
        for (int d = 1; d < 64; d <<= 1) p += __shfl_xor(p, d, 64);
        if (cl == 0) out[i0 + r2] = p + fcb[0];
    }
}

// ============================================================================
extern "C" void kernel_launch(void* const* d_in, const int* in_sizes, int n_in,
                              void* d_out, int out_size, void* d_ws, size_t ws_size,
                              hipStream_t stream) {
    const float* x    = (const float*)d_in[0];
    const float* rel  = (const float*)d_in[1];
    const float* Wih0 = (const float*)d_in[2];
    const float* Whh0 = (const float*)d_in[3];
    const float* bih0 = (const float*)d_in[4];
    const float* bhh0 = (const float*)d_in[5];
    const float* Wih1 = (const float*)d_in[6];
    const float* Whh1 = (const float*)d_in[7];
    const float* bih1 = (const float*)d_in[8];
    const float* bhh1 = (const float*)d_in[9];
    const float* W    = (const float*)d_in[10];
    const float* b    = (const float*)d_in[11];
    const float* fcw  = (const float*)d_in[12];
    const float* fcb  = (const float*)d_in[13];
    float* out = (float*)d_out;

    float* xh = (float*)d_ws;          // 2048*64 fp32
    float* ai = xh + 2048 * 64;        // 2048
    float* aj = ai + 2048;             // 2048

    gru_kernel<<<256, 768, 0, stream>>>(x, Wih0, Whh0, bih0, bhh0,
                                        Wih1, Whh1, bih1, bhh1, xh);
    aij_kernel<<<8, 256, 0, stream>>>(xh, W, ai, aj);
    rel_kernel<<<256, 1024, 0, stream>>>(rel, xh, ai, aj, W, b, fcw, fcb, out);
}

// Round 4
// 187.704 us; speedup vs baseline: 5.6588x; 1.4896x over previous
//
#include <hip/hip_runtime.h>
#include <cstddef>

typedef __attribute__((ext_vector_type(8))) short short8;
typedef __attribute__((ext_vector_type(4))) float f32x4;

#define MFMA16(a, b, c) __builtin_amdgcn_mfma_f32_16x16x32_bf16((a), (b), (c), 0, 0, 0)

__device__ __forceinline__ unsigned short f2bf(float f) {
    unsigned u = __float_as_uint(f);
    u = (u + 0x7fffu + ((u >> 16) & 1u)) >> 16;
    return (unsigned short)u;
}
__device__ __forceinline__ float bf2f(unsigned short s) {
    return __uint_as_float(((unsigned)s) << 16);
}
__device__ __forceinline__ float sigm(float v) { return 1.f / (1.f + __expf(-v)); }
__device__ __forceinline__ float tanh_(float v) {
    float a = fabsf(v);
    float e = __expf(-2.f * a);
    float t = (1.f - e) / (1.f + e);
    return v < 0.f ? -t : t;
}

typedef __attribute__((address_space(1))) const void gas_t;
typedef __attribute__((address_space(3))) void las_t;
__device__ __forceinline__ void gld_lds16(const void* g, void* l) {
    __builtin_amdgcn_global_load_lds((gas_t*)g, (las_t*)l, 16, 0, 0);
}

// ============================================================================
// Kernel 1: fused 2-layer GRU (unchanged from R3 — ~60 us, pipelined groups).
// ============================================================================
__launch_bounds__(768, 3)
__global__ void gru_kernel(const float* __restrict__ x,
                           const float* __restrict__ Wih0, const float* __restrict__ Whh0,
                           const float* __restrict__ bih0, const float* __restrict__ bhh0,
                           const float* __restrict__ Wih1, const float* __restrict__ Whh1,
                           const float* __restrict__ bih1, const float* __restrict__ bhh1,
                           float* __restrict__ xhid) {
    __shared__ __align__(16) unsigned short h0h[2][1024], h0l[2][1024];
    __shared__ __align__(16) unsigned short h1h[2][1024], h1l[2][1024];
    __shared__ __align__(16) float P1[2][16][195];
    __shared__ __align__(16) short8 axbuf[2400];

    const int tid  = threadIdx.x;
    const int grp  = tid >> 8;
    const int lane = tid & 63;
    const int gw   = (tid >> 6) & 3;
    const int c    = lane & 15;
    const int q    = lane >> 4;
    const int jj   = gw * 16 + c;

    for (int i = tid; i < 1024; i += 768) {
        h0h[0][i] = 0; h0l[0][i] = 0; h1h[0][i] = 0; h1l[0][i] = 0;
    }
    {
        const float* xb = x + (size_t)blockIdx.x * 8 * 360;
        for (int f = tid; f < 1920; f += 768) {
            const int t = f >> 5, s = (f >> 2) & 7, qq = f & 3;
            unsigned short Hh[6], Ll[6];
#pragma unroll
            for (int d = 0; d < 6; ++d) {
                const float v = xb[s * 360 + d * 60 + t];
                Hh[d] = f2bf(v); Ll[d] = f2bf(v - bf2f(Hh[d]));
            }
            short8 fr;
#pragma unroll
            for (int e = 0; e < 8; ++e) {
                const int k = qq * 8 + e;
                unsigned short u = 0;
                if (k < 6) u = Hh[k];
                else if (k < 12) u = Ll[k - 6];
                else if (k < 18) u = Hh[k - 12];
                fr[e] = (short)u;
            }
            axbuf[t * 40 + s * 5 + qq] = fr;
        }
    }

    const int ka    = q * 8;
    const int swzA0 = c * 64 + (ka ^ ((c & 7) << 3));
    const int swzA1 = c * 64 + ((32 + ka) ^ ((c & 7) << 3));

    __syncthreads();

    if (grp == 0) {
        short8 Bhh[3][2], Bhl[3][2], Bc[3];
#pragma unroll
        for (int g = 0; g < 3; ++g) {
            const int o = g * 64 + jj;
#pragma unroll
            for (int kt = 0; kt < 2; ++kt) {
                const int k0 = kt * 32 + q * 8;
#pragma unroll
                for (int e = 0; e < 8; ++e) {
                    const float v = Whh0[o * 64 + k0 + e];
                    const unsigned short hi = f2bf(v);
                    Bhh[g][kt][e] = (short)hi; Bhl[g][kt][e] = (short)f2bf(v - bf2f(hi));
                }
            }
#pragma unroll
            for (int e = 0; e < 8; ++e) {
                const int ks = q * 8 + e;
                unsigned short bv = 0;
                if (ks < 6)       bv = f2bf(Wih0[o * 6 + ks]);
                else if (ks < 12) bv = f2bf(Wih0[o * 6 + ks - 6]);
                else if (ks < 18) {
                    const float v = Wih0[o * 6 + ks - 12];
                    const unsigned short hi = f2bf(v);
                    bv = f2bf(v - bf2f(hi));
                }
                Bc[g][e] = (short)bv;
            }
        }
        const float br = bih0[jj] + bhh0[jj];
        const float bz = bih0[64 + jj] + bhh0[64 + jj];
        const float bi = bih0[128 + jj];
        const float bh = bhh0[128 + jj];
        float hreg[4] = {0.f, 0.f, 0.f, 0.f};

        for (int it = 0; it < 62; ++it) {
            if (it < 60) {
                const int par = it & 1;
                const short8 ah0 = *(const short8*)&h0h[par][swzA0];
                const short8 ah1 = *(const short8*)&h0h[par][swzA1];
                const short8 al0 = *(const short8*)&h0l[par][swzA0];
                const short8 al1 = *(const short8*)&h0l[par][swzA1];
                const short8 ax  = axbuf[it * 40 + (c & 7) * 5 + q];

                f32x4 accr = {br, br, br, br};
                f32x4 accz = {bz, bz, bz, bz};
                f32x4 acci = {bi, bi, bi, bi};
                f32x4 acch = {bh, bh, bh, bh};

                accr = MFMA16(ah0, Bhh[0][0], accr); accr = MFMA16(ah1, Bhh[0][1], accr);
                accr = MFMA16(al0, Bhh[0][0], accr); accr = MFMA16(al1, Bhh[0][1], accr);
                accr = MFMA16(ah0, Bhl[0][0], accr); accr = MFMA16(ah1, Bhl[0][1], accr);
                accr = MFMA16(ax, Bc[0], accr);

                accz = MFMA16(ah0, Bhh[1][0], accz); accz = MFMA16(ah1, Bhh[1][1], accz);
                accz = MFMA16(al0, Bhh[1][0], accz); accz = MFMA16(al1, Bhh[1][1], accz);
                accz = MFMA16(ah0, Bhl[1][0], accz); accz = MFMA16(ah1, Bhl[1][1], accz);
                accz = MFMA16(ax, Bc[1], accz);

                acci = MFMA16(ax, Bc[2], acci);

                acch = MFMA16(ah0, Bhh[2][0], acch); acch = MFMA16(ah1, Bhh[2][1], acch);
                acch = MFMA16(al0, Bhh[2][0], acch); acch = MFMA16(al1, Bhh[2][1], acch);
                acch = MFMA16(ah0, Bhl[2][0], acch); acch = MFMA16(ah1, Bhl[2][1], acch);

#pragma unroll
                for (int i2 = 0; i2 < 4; ++i2) {
                    const float rr = sigm(accr[i2]);
                    const float zz = sigm(accz[i2]);
                    const float nn = tanh_(acci[i2] + rr * acch[i2]);
                    const float hv = (1.f - zz) * nn + zz * hreg[i2];
                    hreg[i2] = hv;
                    const int r  = q * 4 + i2;
                    const int ix = r * 64 + (jj ^ ((r & 7) << 3));
                    const unsigned short hi = f2bf(hv);
                    h0h[par ^ 1][ix] = hi;
                    h0l[par ^ 1][ix] = f2bf(hv - bf2f(hi));
                }
            }
            __syncthreads();
        }
    } else if (grp == 1) {
        short8 Bih[3][2], Bil[3][2];
#pragma unroll
        for (int g = 0; g < 3; ++g) {
            const int o = g * 64 + jj;
#pragma unroll
            for (int kt = 0; kt < 2; ++kt) {
                const int k0 = kt * 32 + q * 8;
#pragma unroll
                for (int e = 0; e < 8; ++e) {
                    const float v = Wih1[o * 64 + k0 + e];
                    const unsigned short hi = f2bf(v);
                    Bih[g][kt][e] = (short)hi; Bil[g][kt][e] = (short)f2bf(v - bf2f(hi));
                }
            }
        }
        const float br = bih1[jj] + bhh1[jj];
        const float bz = bih1[64 + jj] + bhh1[64 + jj];
        const float bi = bih1[128 + jj];

        for (int it = 0; it < 62; ++it) {
            if (it >= 1 && it < 61) {
                const int par = it & 1;
                const short8 gh0 = *(const short8*)&h0h[par][swzA0];
                const short8 gh1 = *(const short8*)&h0h[par][swzA1];
                const short8 gl0 = *(const short8*)&h0l[par][swzA0];
                const short8 gl1 = *(const short8*)&h0l[par][swzA1];

                f32x4 ar = {br, br, br, br};
                f32x4 az = {bz, bz, bz, bz};
                f32x4 an = {bi, bi, bi, bi};

                ar = MFMA16(gh0, Bih[0][0], ar); ar = MFMA16(gh1, Bih[0][1], ar);
                ar = MFMA16(gl0, Bih[0][0], ar); ar = MFMA16(gl1, Bih[0][1], ar);
                ar = MFMA16(gh0, Bil[0][0], ar); ar = MFMA16(gh1, Bil[0][1], ar);

                az = MFMA16(gh0, Bih[1][0], az); az = MFMA16(gh1, Bih[1][1], az);
                az = MFMA16(gl0, Bih[1][0], az); az = MFMA16(gl1, Bih[1][1], az);
                az = MFMA16(gh0, Bil[1][0], az); az = MFMA16(gh1, Bil[1][1], az);

                an = MFMA16(gh0, Bih[2][0], an); an = MFMA16(gh1, Bih[2][1], an);
                an = MFMA16(gl0, Bih[2][0], an); an = MFMA16(gl1, Bih[2][1], an);
                an = MFMA16(gh0, Bil[2][0], an); an = MFMA16(gh1, Bil[2][1], an);

#pragma unroll
                for (int i2 = 0; i2 < 4; ++i2) {
                    const int r = q * 4 + i2;
                    P1[par][r][jj]       = ar[i2];
                    P1[par][r][64 + jj]  = az[i2];
                    P1[par][r][128 + jj] = an[i2];
                }
            }
            __syncthreads();
        }
    } else {
        short8 Bhh[3][2], Bhl[3][2];
#pragma unroll
        for (int g = 0; g < 3; ++g) {
            const int o = g * 64 + jj;
#pragma unroll
            for (int kt = 0; kt < 2; ++kt) {
                const int k0 = kt * 32 + q * 8;
#pragma unroll
                for (int e = 0; e < 8; ++e) {
                    const float v = Whh1[o * 64 + k0 + e];
                    const unsigned short hi = f2bf(v);
                    Bhh[g][kt][e] = (short)hi; Bhl[g][kt][e] = (short)f2bf(v - bf2f(hi));
                }
            }
        }
        const float bh = bhh1[128 + jj];
        float hreg[4] = {0.f, 0.f, 0.f, 0.f};

        for (int it = 0; it < 62; ++it) {
            if (it >= 2) {
                const int par = it & 1;
                const short8 hh0 = *(const short8*)&h1h[par][swzA0];
                const short8 hh1_ = *(const short8*)&h1h[par][swzA1];
                const short8 hl0 = *(const short8*)&h1l[par][swzA0];
                const short8 hl1_ = *(const short8*)&h1l[par][swzA1];

                float p1r[4], p1z[4], p1n[4];
#pragma unroll
                for (int i2 = 0; i2 < 4; ++i2) {
                    const int r = q * 4 + i2;
                    p1r[i2] = P1[par ^ 1][r][jj];
                    p1z[i2] = P1[par ^ 1][r][64 + jj];
                    p1n[i2] = P1[par ^ 1][r][128 + jj];
                }

                f32x4 ar  = {p1r[0], p1r[1], p1r[2], p1r[3]};
                f32x4 az  = {p1z[0], p1z[1], p1z[2], p1z[3]};
                f32x4 ahn = {bh, bh, bh, bh};

                ar = MFMA16(hh0, Bhh[0][0], ar); ar = MFMA16(hh1_, Bhh[0][1], ar);
                ar = MFMA16(hl0, Bhh[0][0], ar); ar = MFMA16(hl1_, Bhh[0][1], ar);
                ar = MFMA16(hh0, Bhl[0][0], ar); ar = MFMA16(hh1_, Bhl[0][1], ar);

                az = MFMA16(hh0, Bhh[1][0], az); az = MFMA16(hh1_, Bhh[1][1], az);
                az = MFMA16(hl0, Bhh[1][0], az); az = MFMA16(hl1_, Bhh[1][1], az);
                az = MFMA16(hh0, Bhl[1][0], az); az = MFMA16(hh1_, Bhl[1][1], az);

                ahn = MFMA16(hh0, Bhh[2][0], ahn); ahn = MFMA16(hh1_, Bhh[2][1], ahn);
                ahn = MFMA16(hl0, Bhh[2][0], ahn); ahn = MFMA16(hl1_, Bhh[2][1], ahn);
                ahn = MFMA16(hh0, Bhl[2][0], ahn); ahn = MFMA16(hh1_, Bhl[2][1], ahn);

#pragma unroll
                for (int i2 = 0; i2 < 4; ++i2) {
                    const float rr = sigm(ar[i2]);
                    const float zz = sigm(az[i2]);
                    const float nn = tanh_(p1n[i2] + rr * ahn[i2]);
                    const float hv = (1.f - zz) * nn + zz * hreg[i2];
                    hreg[i2] = hv;
                    const int r  = q * 4 + i2;
                    const int ix = r * 64 + (jj ^ ((r & 7) << 3));
                    const unsigned short hi = f2bf(hv);
                    h1h[par ^ 1][ix] = hi;
                    h1l[par ^ 1][ix] = f2bf(hv - bf2f(hi));
                    if (it == 61 && q < 2)
                        xhid[((size_t)blockIdx.x * 8 + r) * 64 + jj] = hv;
                }
            }
            __syncthreads();
        }
    }
}

// ============================================================================
// Kernel 2: ai[n] = x_hidden[n] . W1 ; aj[n] = x_hidden[n] . W2
// ============================================================================
__global__ void aij_kernel(const float* __restrict__ xh, const float* __restrict__ W,
                           float* __restrict__ ai, float* __restrict__ aj) {
    const int n = blockIdx.x * 256 + threadIdx.x;
    const float* row = xh + (size_t)n * 64;
    float a1 = 0.f, a2 = 0.f;
#pragma unroll
    for (int k = 0; k < 64; k += 4) {
        const f32x4 v = *(const f32x4*)(row + k);
#pragma unroll
        for (int u = 0; u < 4; ++u) {
            a1 += v[u] * W[k + u];
            a2 += v[u] * W[64 + k + u];
        }
    }
    ai[n] = a1;
    aj[n] = a2;
}

// ============================================================================
// Kernel 3: fused relation pass, v3. 1024 blocks x 256 threads, 2 rows/block.
// R3's counters: 1.44 TB/s, VALUBusy 9%, occupancy 45% -> NOT latency-bound;
// killer was 80-B-stride 16B gathers (each wave-load scatters over ~40 lines).
// v3 stages rel chunks into LDS with DENSE lane-contiguous global_load_lds
// (1 KB/instr), double-buffered, counted vmcnt(5) + raw s_barrier so prefetch
// stays in flight across barriers (T3/T4). All compiler VMEM confined to the
// prologue (scalars via LDS) so the vmcnt count stays exact.
// Score math from LDS: stride-80 ds_read_b128 (~8-way conflict, hidden under
// the 53-us HBM stream). LDS ~68 KB -> 2 blocks/CU.
// ============================================================================
__launch_bounds__(256, 2)
__global__ void rel_kernel(const float* __restrict__ rel, const float* __restrict__ xh,
                           const float* __restrict__ ai, const float* __restrict__ aj,
                           const float* __restrict__ W, const float* __restrict__ bptr,
                           const float* __restrict__ fcw, const float* __restrict__ fcb,
                           float* __restrict__ out) {
    __shared__ __align__(16) unsigned char stage[2][2][10240];  // [buf][row][j*80B]
    __shared__ __align__(16) float pexp[2][2048];
    __shared__ __align__(16) float aj_s[2048];
    __shared__ float w3b_s[24];
    __shared__ float hidpart[4][2][64];
    __shared__ float redm[2][2], reds[2][2], rinv_s[2];

    const int tid  = threadIdx.x;
    const int lane = tid & 63;
    const int wv   = tid >> 6;        // wave 0..3
    const int i0   = blockIdx.x * 2;

    // ---- prologue: all compiler-generated global loads happen here ----
    for (int k = tid; k < 2048; k += 256) aj_s[k] = aj[k];
    if (tid < 20) w3b_s[tid] = W[128 + tid];
    if (tid == 20) w3b_s[20] = bptr[0];
    if (tid < 2)  w3b_s[21 + tid] = ai[i0 + tid];
    __syncthreads();   // drains vmcnt(0)

    float w3[20];
#pragma unroll
    for (int r = 0; r < 20; ++r) w3[r] = w3b_s[r];
    const float bb  = w3b_s[20];
    const float aiv = (tid >> 7) ? w3b_s[22] : w3b_s[21];

    const int r_ = tid >> 7;      // row this thread scores (0/1)
    const int t7 = tid & 127;     // j within chunk

    // ---- stage chunk 0 (each wave: 5 x 1KB dense global_load_lds) ----
#pragma unroll
    for (int k = 0; k < 5; ++k) {
        const int m = wv + 4 * k;           // 0..19
        const int rr = m / 10, oo = (m % 10) * 1024;
        const unsigned char* g =
            (const unsigned char*)(rel + (size_t)(i0 + rr) * 2048 * 20) + oo + lane * 16;
        gld_lds16(g, &stage[0][rr][oo]);
    }

    // ---- pipelined chunk loop: 16 chunks of 128 j ----
    for (int c = 0; c < 16; ++c) {
        const int buf = c & 1;
        if (c < 15) {
#pragma unroll
            for (int k = 0; k < 5; ++k) {
                const int m = wv + 4 * k;
                const int rr = m / 10, oo = (m % 10) * 1024;
                const unsigned char* g =
                    (const unsigned char*)(rel + ((size_t)(i0 + rr) * 2048 + (size_t)(c + 1) * 128) * 20)
                    + oo + lane * 16;
                gld_lds16(g, &stage[buf ^ 1][rr][oo]);
            }
            asm volatile("s_waitcnt vmcnt(5)" ::: "memory");   // chunk c landed
        } else {
            asm volatile("s_waitcnt vmcnt(0)" ::: "memory");
        }
        __builtin_amdgcn_s_barrier();
        __builtin_amdgcn_sched_barrier(0);

        // score for pair (row r_, j = c*128 + t7) from LDS
        const unsigned char* sp = &stage[buf][r_][t7 * 80];
        float arv = 0.f, ms = 0.f;
#pragma unroll
        for (int e = 0; e < 5; ++e) {
            const f32x4 v = *(const f32x4*)(sp + e * 16);
            arv += v[0] * w3[e * 4] + v[1] * w3[e * 4 + 1]
                 + v[2] * w3[e * 4 + 2] + v[3] * w3[e * 4 + 3];
            ms += v[0] + v[1] + v[2] + v[3];
        }
        const int j = c * 128 + t7;
        float wvv = aiv + aj_s[j] + arv + bb;
        wvv = (wvv >= 0.f) ? wvv : 0.01f * wvv;
        pexp[r_][j] = (ms != 0.f) ? wvv : 0.f;
        __builtin_amdgcn_s_barrier();   // all reads of stage[buf] done before re-stage
    }
    __syncthreads();

    // ---- phase B: row softmax (128 threads = 2 waves per row) ----
    const int c7 = tid & 127;
    const int wh = (tid >> 6) & 1;
    float mx = -1e30f;
#pragma unroll
    for (int m = 0; m < 16; ++m) mx = fmaxf(mx, pexp[r_][c7 + 128 * m]);
#pragma unroll
    for (int d = 1; d < 64; d <<= 1) mx = fmaxf(mx, __shfl_xor(mx, d, 64));
    if (lane == 0) redm[r_][wh] = mx;
    __syncthreads();
    mx = fmaxf(redm[r_][0], redm[r_][1]);

    float sm = 0.f;
#pragma unroll
    for (int m = 0; m < 16; ++m) {
        const int k = c7 + 128 * m;
        const float e = __expf(pexp[r_][k] - mx);
        pexp[r_][k] = e;
        sm += e;
    }
#pragma unroll
    for (int d = 1; d < 64; d <<= 1) sm += __shfl_xor(sm, d, 64);
    if (lane == 0) reds[r_][wh] = sm;
    __syncthreads();
    if (tid < 2) rinv_s[tid] = 1.f / (reds[tid][0] + reds[tid][1]);
    __syncthreads();

    // ---- phase C: hidden = p @ x_hidden (wave = 512-row K-strip, lane = col) ----
    const int col = lane;
    const int k0s = wv * 512;
    float acc0 = 0.f, acc1 = 0.f;
    for (int k = 0; k < 512; k += 4) {
        const float v0 = xh[(size_t)(k0s + k) * 64 + col];
        const float v1 = xh[(size_t)(k0s + k + 1) * 64 + col];
        const float v2 = xh[(size_t)(k0s + k + 2) * 64 + col];
        const float v3 = xh[(size_t)(k0s + k + 3) * 64 + col];
        const f32x4 e0 = *(const f32x4*)&pexp[0][k0s + k];
        const f32x4 e1 = *(const f32x4*)&pexp[1][k0s + k];
        acc0 += e0[0] * v0 + e0[1] * v1 + e0[2] * v2 + e0[3] * v3;
        acc1 += e1[0] * v0 + e1[1] * v1 + e1[2] * v2 + e1[3] * v3;
    }
    hidpart[wv][0][col] = acc0;
    hidpart[wv][1][col] = acc1;
    __syncthreads();

    // ---- phase D: reduce strips + residual + fc ----
    if (tid < 128) {
        const int r2 = tid >> 6, cl = lane;
        float hs = hidpart[0][r2][cl] + hidpart[1][r2][cl]
                 + hidpart[2][r2][cl] + hidpart[3][r2][cl];
        const float h = hs * rinv_s[r2] + xh[(size_t)(i0 + r2) * 64 + cl];
        float p = h * fcw[cl];
#pragma unroll
        for (int d = 1; d < 64; d <<= 1) p += __shfl_xor(p, d, 64);
        if (cl == 0) out[i0 + r2] = p + fcb[0];
    }
}

// ============================================================================
extern "C" void kernel_launch(void* const* d_in, const int* in_sizes, int n_in,
                              void* d_out, int out_size, void* d_ws, size_t ws_size,
                              hipStream_t stream) {
    const float* x    = (const float*)d_in[0];
    const float* rel  = (const float*)d_in[1];
    const float* Wih0 = (const float*)d_in[2];
    const float* Whh0 = (const float*)d_in[3];
    const float* bih0 = (const float*)d_in[4];
    const float* bhh0 = (const float*)d_in[5];
    const float* Wih1 = (const float*)d_in[6];
    const float* Whh1 = (const float*)d_in[7];
    const float* bih1 = (const float*)d_in[8];
    const float* bhh1 = (const float*)d_in[9];
    const float* W    = (const float*)d_in[10];
    const float* b    = (const float*)d_in[11];
    const float* fcw  = (const float*)d_in[12];
    const float* fcb  = (const float*)d_in[13];
    float* out = (float*)d_out;

    float* xh = (float*)d_ws;          // 2048*64 fp32
    float* ai = xh + 2048 * 64;        // 2048
    float* aj = ai + 2048;             // 2048

    gru_kernel<<<256, 768, 0, stream>>>(x, Wih0, Whh0, bih0, bhh0,
                                        Wih1, Whh1, bih1, bhh1, xh);
    aij_kernel<<<8, 256, 0, stream>>>(xh, W, ai, aj);
    rel_kernel<<<1024, 256, 0, stream>>>(rel, xh, ai, aj, W, b, fcw, fcb, out);
}